// Round 5
// baseline (260.852 us; speedup 1.0000x reference)
//
#include <hip/hip_runtime.h>
#include <hip/hip_bf16.h>
#include <stdint.h>

#define Bsz 4096
#define Dn  512
#define Kn  128
#define Pn  16
#define An  32
#define TB  16

typedef __attribute__((ext_vector_type(4))) float  floatx4;
typedef __attribute__((ext_vector_type(8))) short  shortx8;

// Scratch in module-scope device memory (d_ws unused; harness poison fills
// are unconditional — verified round 3).
__device__ unsigned short g_mu_bf[Kn * Dn];
__device__ unsigned short g_mu_t[Dn * Kn];
__device__ float          g_munorm[Kn];

__device__ __forceinline__ unsigned short f2bf(float x) {
    union { float f; uint32_t u; } v; v.f = x;
    uint32_t u = v.u;
    uint32_t r = (u + 0x7FFFu + ((u >> 16) & 1u)) >> 16;
    return (unsigned short)r;
}

// Sum over the 16 lanes of a DPP row (m = lane&15), pure VALU (no LDS).
__device__ __forceinline__ float rowsum16(float x) {
    x += __int_as_float(__builtin_amdgcn_update_dpp(0, __float_as_int(x), 0xB1, 0xF, 0xF, false));
    x += __int_as_float(__builtin_amdgcn_update_dpp(0, __float_as_int(x), 0x4E, 0xF, 0xF, false));
    x += __int_as_float(__builtin_amdgcn_update_dpp(0, __float_as_int(x), 0x124, 0xF, 0xF, false));
    x += __int_as_float(__builtin_amdgcn_update_dpp(0, __float_as_int(x), 0x128, 0xF, 0xF, false));
    return x;
}

// ---------------- K1: mu = alpha @ W (bf16 row-major + bf16 transposed) + ||mu_k||^2 ----------------
__global__ __launch_bounds__(256) void k_mu(const float* __restrict__ alpha,
                                            const float* __restrict__ W,
                                            float* __restrict__ out) {
    __shared__ float al[An];
    __shared__ float red[4];
    int k = blockIdx.x, t = threadIdx.x;
    if (k == 0 && t == 0) *out = 0.f;        // replaces the memset dispatch
    if (t < An) al[t] = alpha[k * An + t];
    __syncthreads();
    int d0 = t, d1 = t + 256;
    float a0 = 0.f, a1 = 0.f;
#pragma unroll
    for (int a = 0; a < An; ++a) {
        float av = al[a];
        a0 = fmaf(av, W[a * Dn + d0], a0);
        a1 = fmaf(av, W[a * Dn + d1], a1);
    }
    unsigned short h0 = f2bf(a0), h1 = f2bf(a1);
    g_mu_bf[k * Dn + d0] = h0;  g_mu_bf[k * Dn + d1] = h1;
    // transposed copy: mu_t[d][k] -> contiguous-in-k shortx8 B-fragments for w@mu
    g_mu_t[d0 * Kn + k] = h0;   g_mu_t[d1 * Kn + k] = h1;
    float nrm = a0 * a0 + a1 * a1;
#pragma unroll
    for (int msk = 1; msk < 64; msk <<= 1) nrm += __shfl_xor(nrm, msk);
    if ((t & 63) == 0) red[t >> 6] = nrm;
    __syncthreads();
    if (t == 0) g_munorm[k] = red[0] + red[1] + red[2] + red[3];
}

// ---------------- K3: fused S/softmax/wGw + streaming probe contraction ----------------
// Round-5 change: kill the VGPR spill (round-4 PMC: VGPR_Count=64 forced,
// WRITE_SIZE 20 MB of scratch — mufrag[16]=64 VGPR persistent + buf overflowed
// the 128-reg tier). mu B-fragments are now STREAMED from L2-resident
// g_mu_bf with a 4-deep rotating register window (16 VGPR, static indices).
__global__ __launch_bounds__(512, 4) void k_main(
    const float* __restrict__ thetas,
    const int* __restrict__ v_int,
    const int* __restrict__ Np,
    float* __restrict__ out)
{
    __shared__ short vt[2][TB][520];
    __shared__ float S_l[TB][132];
    __shared__ float w_l[TB][132];
    __shared__ short wbf[TB][136];
    __shared__ float part[2][8][TB][2];
    __shared__ float thn[TB];
    __shared__ float SwS[TB];

    const int tid = threadIdx.x;
    const int lane = tid & 63;
    const int wv = tid >> 6;
    const int m = lane & 15;
    const int q = lane >> 4;

    const int tileb = blockIdx.x >> 1;
    const int phalf = blockIdx.x & 1;
    const int b0 = tileb * TB;
    const int p0 = phalf * 8;

    const float Nf = (float)(*Np);
    const float temper = Nf / (Nf + 1.0f);

    const int kcol = wv * 16 + m;
    // B-fragment base: frag dc lives at mb + dc*32 (L2/L3-resident, reused 9x)
    const unsigned short* mb = g_mu_bf + (size_t)kcol * Dn + q * 8;

    const int r = tid >> 5;
    const int c0 = (tid & 31) * 16;
    const size_t PB = (size_t)Bsz * Dn;
    const int* vrow = v_int + (size_t)(b0 + r) * Dn + c0;

    int4 buf[2][4];
    {   // prefetch probes p0 and p0+1 (land during prologue)
        const int4* gA = (const int4*)(vrow + (size_t)p0 * PB);
        const int4* gB = (const int4*)(vrow + (size_t)(p0 + 1) * PB);
#pragma unroll
        for (int j = 0; j < 4; ++j) buf[0][j] = gA[j];
#pragma unroll
        for (int j = 0; j < 4; ++j) buf[1][j] = gB[j];
    }
    {   // stage theta -> vt[0] (bf16), ||theta||^2 fp32
        const float4* tg = (const float4*)(thetas + (size_t)(b0 + r) * Dn + c0);
        float tn = 0.f;
#pragma unroll
        for (int j = 0; j < 4; ++j) {
            float4 f = tg[j];
            tn += f.x * f.x + f.y * f.y + f.z * f.z + f.w * f.w;
            short4 h;
            h.x = (short)f2bf(f.x); h.y = (short)f2bf(f.y);
            h.z = (short)f2bf(f.z); h.w = (short)f2bf(f.w);
            *(short4*)&vt[0][r][c0 + j * 4] = h;
        }
#pragma unroll
        for (int msk = 1; msk < 32; msk <<= 1) tn += __shfl_xor(tn, msk);
        if ((tid & 31) == 0) thn[r] = tn;
    }
    __syncthreads();

    // ---- S = theta @ mu^T  (mu frags streamed, 4-deep window) ----
    {
        shortx8 fr[4];
#pragma unroll
        for (int i = 0; i < 4; ++i) fr[i] = *(const shortx8*)(mb + i * 32);
        floatx4 acc = {0.f, 0.f, 0.f, 0.f};
#pragma unroll
        for (int dc = 0; dc < 16; ++dc) {
            shortx8 a = *(const shortx8*)&vt[0][m][dc * 32 + q * 8];
            shortx8 b = fr[dc & 3];
            if (dc < 12) fr[dc & 3] = *(const shortx8*)(mb + (dc + 4) * 32);
            acc = __builtin_amdgcn_mfma_f32_16x16x32_bf16(a, b, acc, 0, 0, 0);
        }
#pragma unroll
        for (int i = 0; i < 4; ++i) S_l[q * 4 + i][kcol] = acc[i];
    }
    __syncthreads();

    // ---- softmax over k (32 threads per b-row) ----
    {
        const int b = tid >> 5, s = tid & 31;
        float l[4];
        float mx = -3.4e38f;
        float tnb = thn[b];
#pragma unroll
        for (int j = 0; j < 4; ++j) {
            int k = s + 32 * j;
            l[j] = -0.5f * (tnb - 2.f * S_l[b][k] + g_munorm[k]);
            mx = fmaxf(mx, l[j]);
        }
#pragma unroll
        for (int msk = 1; msk < 32; msk <<= 1) mx = fmaxf(mx, __shfl_xor(mx, msk));
        float se = 0.f, ses = 0.f;
        float e[4];
#pragma unroll
        for (int j = 0; j < 4; ++j) {
            int k = s + 32 * j;
            e[j] = __expf(l[j] - mx);
            se += e[j];
            ses += e[j] * S_l[b][k];
        }
#pragma unroll
        for (int msk = 1; msk < 32; msk <<= 1) { se += __shfl_xor(se, msk); ses += __shfl_xor(ses, msk); }
        float inv = 1.f / se;
#pragma unroll
        for (int j = 0; j < 4; ++j) {
            int k = s + 32 * j;
            float wvv = e[j] * inv;
            w_l[b][k] = wvv;
            wbf[b][k] = (short)f2bf(wvv);
        }
        if (s == 0) SwS[b] = ses * inv;
    }
    __syncthreads();

    // ---- wGw = ||y||^2 with y = w @ mu  (from g_mu_t, L2-resident) ----
    {
        float sg[4] = {0.f, 0.f, 0.f, 0.f};
#pragma unroll
        for (int ct = 0; ct < 4; ++ct) {
            const unsigned short* mt = g_mu_t + (size_t)(wv * 64 + ct * 16 + m) * Kn + q * 8;
            floatx4 acc = {0.f, 0.f, 0.f, 0.f};
#pragma unroll
            for (int kc = 0; kc < 4; ++kc) {
                shortx8 a = *(const shortx8*)&wbf[m][kc * 32 + q * 8];
                shortx8 bfr = *(const shortx8*)(mt + kc * 32);
                acc = __builtin_amdgcn_mfma_f32_16x16x32_bf16(a, bfr, acc, 0, 0, 0);
            }
#pragma unroll
            for (int i = 0; i < 4; ++i) sg[i] += acc[i] * acc[i];
        }
#pragma unroll
        for (int i = 0; i < 4; ++i) sg[i] = rowsum16(sg[i]);
        if (m == 0) {
#pragma unroll
            for (int i = 0; i < 4; ++i) part[0][wv][q * 4 + i][0] = sg[i];
        }
    }

    // hoist loop-invariant softmax weights (w_l stable since softmax barrier)
    float wt4[4];
#pragma unroll
    for (int i = 0; i < 4; ++i) wt4[i] = w_l[q * 4 + i][kcol];
    __syncthreads();

    float lossA = 0.f, tracc = 0.f;
    if (tid < TB) {
        float wGw = 0.f;
#pragma unroll
        for (int w8 = 0; w8 < 8; ++w8) wGw += part[0][w8][tid][0];
        if (phalf == 0)
            lossA = 0.5f * temper * temper * (wGw - 2.f * SwS[tid] + thn[tid])
                    - temper * (float)Dn;
    }

    // ---- probe loop: 1 barrier per probe, 2-deep prefetch, streamed mu ----
#pragma unroll
    for (int p = 0; p < 8; ++p) {
        // convert buf[p&1] (probe p, loaded 2 iterations ago) -> vt[p&1]
        // bf16(2v-1): v=1 -> 0x3F80, v=0 -> 0xBF80 == 0xBF80 ^ (v<<15)
#pragma unroll
        for (int j = 0; j < 2; ++j) {
            int4 a = buf[p & 1][2 * j], b = buf[p & 1][2 * j + 1];
            uint32_t l0 = 0xBF80BF80u ^ ((uint32_t)a.x << 15) ^ ((uint32_t)a.y << 31);
            uint32_t l1 = 0xBF80BF80u ^ ((uint32_t)a.z << 15) ^ ((uint32_t)a.w << 31);
            uint32_t l2 = 0xBF80BF80u ^ ((uint32_t)b.x << 15) ^ ((uint32_t)b.y << 31);
            uint32_t l3 = 0xBF80BF80u ^ ((uint32_t)b.z << 15) ^ ((uint32_t)b.w << 31);
            uint4 pk; pk.x = l0; pk.y = l1; pk.z = l2; pk.w = l3;
            *(uint4*)&vt[p & 1][r][c0 + j * 8] = pk;
        }
        __syncthreads();
        // refill the just-consumed buffer with probe p+2 (2 iterations of slack)
        if (p < 6) {
            const int4* g = (const int4*)(vrow + (size_t)(p0 + p + 2) * PB);
#pragma unroll
            for (int j = 0; j < 4; ++j) buf[p & 1][j] = g[j];
        }
        if (p > 0 && tid < TB) {
            float S1 = 0.f, S2 = 0.f;
#pragma unroll
            for (int w8 = 0; w8 < 8; ++w8) {
                S1 += part[(p - 1) & 1][w8][tid][0];
                S2 += part[(p - 1) & 1][w8][tid][1];
            }
            tracc += S1 - S2 * S2;
        }
        floatx4 acc = {0.f, 0.f, 0.f, 0.f};
        {
            shortx8 fr[4];
#pragma unroll
            for (int i = 0; i < 4; ++i) fr[i] = *(const shortx8*)(mb + i * 32);
#pragma unroll
            for (int dc = 0; dc < 16; ++dc) {
                shortx8 a = *(const shortx8*)&vt[p & 1][m][dc * 32 + q * 8];
                shortx8 b = fr[dc & 3];
                if (dc < 12) fr[dc & 3] = *(const shortx8*)(mb + (dc + 4) * 32);
                acc = __builtin_amdgcn_mfma_f32_16x16x32_bf16(a, b, acc, 0, 0, 0);
            }
        }
        float s1[4], s2[4];
#pragma unroll
        for (int i = 0; i < 4; ++i) {
            float T = acc[i];
            s1[i] = wt4[i] * T * T;
            s2[i] = wt4[i] * T;
        }
#pragma unroll
        for (int i = 0; i < 4; ++i) {
            s1[i] = rowsum16(s1[i]);
            s2[i] = rowsum16(s2[i]);
        }
        if (m == 0) {
#pragma unroll
            for (int i = 0; i < 4; ++i) {
                part[p & 1][wv][q * 4 + i][0] = s1[i];
                part[p & 1][wv][q * 4 + i][1] = s2[i];
            }
        }
        // no trailing barrier: next iteration's barrier orders part/vt reuse
    }
    __syncthreads();
    if (tid < TB) {
        float S1 = 0.f, S2 = 0.f;
#pragma unroll
        for (int w8 = 0; w8 < 8; ++w8) {
            S1 += part[1][w8][tid][0];
            S2 += part[1][w8][tid][1];
        }
        tracc += S1 - S2 * S2;
        float res = temper * tracc * (1.0f / (float)Pn) + lossA;
#pragma unroll
        for (int msk = 1; msk < 16; msk <<= 1) res += __shfl_xor(res, msk);
        if (tid == 0) atomicAdd(out, res * (1.0f / (float)Bsz));
    }
}

extern "C" void kernel_launch(void* const* d_in, const int* in_sizes, int n_in,
                              void* d_out, int out_size, void* d_ws, size_t ws_size,
                              hipStream_t stream) {
    const float* thetas = (const float*)d_in[0];
    const float* alpha  = (const float*)d_in[1];
    const float* W      = (const float*)d_in[2];
    const int*   v_int  = (const int*)d_in[3];
    const int*   Np     = (const int*)d_in[4];
    (void)d_ws; (void)ws_size;   // scratch lives in __device__ globals

    float* out = (float*)d_out;
    k_mu  <<<dim3(Kn),  dim3(256), 0, stream>>>(alpha, W, out);
    k_main<<<dim3(512), dim3(512), 0, stream>>>(thetas, v_int, Np, out);
}

// Round 6
// 255.126 us; speedup vs baseline: 1.0224x; 1.0224x over previous
//
#include <hip/hip_runtime.h>
#include <hip/hip_bf16.h>
#include <stdint.h>

#define Bsz 4096
#define Dn  512
#define Kn  128
#define Pn  16
#define An  32
#define TB  16

typedef __attribute__((ext_vector_type(4))) float  floatx4;
typedef __attribute__((ext_vector_type(8))) short  shortx8;

// Module-scope scratch (d_ws unused — harness poison fills are unconditional).
__device__ unsigned short g_mu_bf[Kn * Dn];
__device__ unsigned short g_mu_t[Dn * Kn];
__device__ float          g_munorm[Kn];
__device__ float          g_w[Bsz * Kn];       // softmax weights, f32 (2 MB, L2/L3)

__device__ __forceinline__ unsigned short f2bf(float x) {
    union { float f; uint32_t u; } v; v.f = x;
    uint32_t u = v.u;
    uint32_t r = (u + 0x7FFFu + ((u >> 16) & 1u)) >> 16;
    return (unsigned short)r;
}

// Sum over the 16 lanes of a DPP row (m = lane&15), pure VALU.
__device__ __forceinline__ float rowsum16(float x) {
    x += __int_as_float(__builtin_amdgcn_update_dpp(0, __float_as_int(x), 0xB1, 0xF, 0xF, false));
    x += __int_as_float(__builtin_amdgcn_update_dpp(0, __float_as_int(x), 0x4E, 0xF, 0xF, false));
    x += __int_as_float(__builtin_amdgcn_update_dpp(0, __float_as_int(x), 0x124, 0xF, 0xF, false));
    x += __int_as_float(__builtin_amdgcn_update_dpp(0, __float_as_int(x), 0x128, 0xF, 0xF, false));
    return x;
}

// ---------------- K1: mu = alpha @ W (bf16 + transposed) + ||mu_k||^2 ----------------
__global__ __launch_bounds__(256) void k_mu(const float* __restrict__ alpha,
                                            const float* __restrict__ W,
                                            float* __restrict__ out) {
    __shared__ float al[An];
    __shared__ float red[4];
    int k = blockIdx.x, t = threadIdx.x;
    if (k == 0 && t == 0) *out = 0.f;
    if (t < An) al[t] = alpha[k * An + t];
    __syncthreads();
    int d0 = t, d1 = t + 256;
    float a0 = 0.f, a1 = 0.f;
#pragma unroll
    for (int a = 0; a < An; ++a) {
        float av = al[a];
        a0 = fmaf(av, W[a * Dn + d0], a0);
        a1 = fmaf(av, W[a * Dn + d1], a1);
    }
    unsigned short h0 = f2bf(a0), h1 = f2bf(a1);
    g_mu_bf[k * Dn + d0] = h0;  g_mu_bf[k * Dn + d1] = h1;
    g_mu_t[d0 * Kn + k] = h0;   g_mu_t[d1 * Kn + k] = h1;
    float nrm = a0 * a0 + a1 * a1;
#pragma unroll
    for (int msk = 1; msk < 64; msk <<= 1) nrm += __shfl_xor(nrm, msk);
    if ((t & 63) == 0) red[t >> 6] = nrm;
    __syncthreads();
    if (t == 0) g_munorm[k] = red[0] + red[1] + red[2] + red[3];
}

// ---------------- K2: S = theta@mu^T, softmax -> g_w, wGw + lossA ----------------
// One block per 16-row b-tile (grid 256). No probe work. No min-occupancy bound
// (VGPR-heavy mufrag[16] is fine here — short kernel).
__global__ __launch_bounds__(512) void k_w(const float* __restrict__ thetas,
                                           const int* __restrict__ Np,
                                           float* __restrict__ out) {
    __shared__ short vt[TB][520];
    __shared__ float S_l[TB][132];
    __shared__ float w_l[TB][132];
    __shared__ short wbf[TB][136];
    __shared__ float part8[8][TB];
    __shared__ float thn[TB];
    __shared__ float SwS[TB];

    const int tid = threadIdx.x;
    const int lane = tid & 63;
    const int wv = tid >> 6;
    const int m = lane & 15;
    const int q = lane >> 4;
    const int b0 = blockIdx.x * TB;

    const float Nf = (float)(*Np);
    const float temper = Nf / (Nf + 1.0f);

    const int kcol = wv * 16 + m;
    shortx8 mufrag[16];
    {
        const unsigned short* mb = g_mu_bf + (size_t)kcol * Dn + q * 8;
#pragma unroll
        for (int dc = 0; dc < 16; ++dc)
            mufrag[dc] = *(const shortx8*)(mb + dc * 32);
    }

    const int r = tid >> 5;
    const int c0 = (tid & 31) * 16;
    {   // stage theta -> vt (bf16), ||theta||^2 fp32
        const float4* tg = (const float4*)(thetas + (size_t)(b0 + r) * Dn + c0);
        float tn = 0.f;
#pragma unroll
        for (int j = 0; j < 4; ++j) {
            float4 f = tg[j];
            tn += f.x * f.x + f.y * f.y + f.z * f.z + f.w * f.w;
            short4 h;
            h.x = (short)f2bf(f.x); h.y = (short)f2bf(f.y);
            h.z = (short)f2bf(f.z); h.w = (short)f2bf(f.w);
            *(short4*)&vt[r][c0 + j * 4] = h;
        }
#pragma unroll
        for (int msk = 1; msk < 32; msk <<= 1) tn += __shfl_xor(tn, msk);
        if ((tid & 31) == 0) thn[r] = tn;
    }
    __syncthreads();

    // ---- S = theta @ mu^T ----
    {
        floatx4 acc = {0.f, 0.f, 0.f, 0.f};
#pragma unroll
        for (int dc = 0; dc < 16; ++dc) {
            shortx8 a = *(const shortx8*)&vt[m][dc * 32 + q * 8];
            acc = __builtin_amdgcn_mfma_f32_16x16x32_bf16(a, mufrag[dc], acc, 0, 0, 0);
        }
#pragma unroll
        for (int i = 0; i < 4; ++i) S_l[q * 4 + i][kcol] = acc[i];
    }
    __syncthreads();

    // ---- softmax over k (32 threads per b-row); also writes g_w ----
    {
        const int b = tid >> 5, s = tid & 31;
        float l[4];
        float mx = -3.4e38f;
        float tnb = thn[b];
#pragma unroll
        for (int j = 0; j < 4; ++j) {
            int k = s + 32 * j;
            l[j] = -0.5f * (tnb - 2.f * S_l[b][k] + g_munorm[k]);
            mx = fmaxf(mx, l[j]);
        }
#pragma unroll
        for (int msk = 1; msk < 32; msk <<= 1) mx = fmaxf(mx, __shfl_xor(mx, msk));
        float se = 0.f, ses = 0.f;
        float e[4];
#pragma unroll
        for (int j = 0; j < 4; ++j) {
            int k = s + 32 * j;
            e[j] = __expf(l[j] - mx);
            se += e[j];
            ses += e[j] * S_l[b][k];
        }
#pragma unroll
        for (int msk = 1; msk < 32; msk <<= 1) { se += __shfl_xor(se, msk); ses += __shfl_xor(ses, msk); }
        float inv = 1.f / se;
#pragma unroll
        for (int j = 0; j < 4; ++j) {
            int k = s + 32 * j;
            float wvv = e[j] * inv;
            w_l[b][k] = wvv;
            wbf[b][k] = (short)f2bf(wvv);
            g_w[(size_t)(b0 + b) * Kn + k] = wvv;   // coalesced global write
        }
        if (s == 0) SwS[b] = ses * inv;
    }
    __syncthreads();

    // ---- wGw = ||w @ mu||^2 (from g_mu_t, L2-resident) ----
    {
        float sg[4] = {0.f, 0.f, 0.f, 0.f};
#pragma unroll
        for (int ct = 0; ct < 4; ++ct) {
            const unsigned short* mt = g_mu_t + (size_t)(wv * 64 + ct * 16 + m) * Kn + q * 8;
            floatx4 acc = {0.f, 0.f, 0.f, 0.f};
#pragma unroll
            for (int kc = 0; kc < 4; ++kc) {
                shortx8 a = *(const shortx8*)&wbf[m][kc * 32 + q * 8];
                shortx8 bfr = *(const shortx8*)(mt + kc * 32);
                acc = __builtin_amdgcn_mfma_f32_16x16x32_bf16(a, bfr, acc, 0, 0, 0);
            }
#pragma unroll
            for (int i = 0; i < 4; ++i) sg[i] += acc[i] * acc[i];
        }
#pragma unroll
        for (int i = 0; i < 4; ++i) sg[i] = rowsum16(sg[i]);
        if (m == 0) {
#pragma unroll
            for (int i = 0; i < 4; ++i) part8[wv][q * 4 + i] = sg[i];
        }
    }
    __syncthreads();

    if (tid < TB) {
        float wGw = 0.f;
#pragma unroll
        for (int w8 = 0; w8 < 8; ++w8) wGw += part8[w8][tid];
        float res = 0.5f * temper * temper * (wGw - 2.f * SwS[tid] + thn[tid])
                    - temper * (float)Dn;
#pragma unroll
        for (int msk = 1; msk < 16; msk <<= 1) res += __shfl_xor(res, msk);
        if (tid == 0) atomicAdd(out, res * (1.0f / (float)Bsz));
    }
}

// ---------------- K3: barrier-free probe trace ----------------
// Grid 512 = 32 b-tiles (128 rows) x 16 probes; 512 thr = 8 waves; 2 blocks/CU.
// Each wave owns 16 b-rows of one probe, fully independent: v loaded per-lane
// directly in A-frag layout (2x int4, contiguous, coalesced), mu B-frags read
// straight from L2 (128 KB, resident per XCD), all 8 k-tiles accumulated in
// regs. NO __syncthreads in the hot path -> waves slip freely, memory issue
// is continuous (fixes the r3-r5 barrier convoy: all pipes <11%, 24k cyc/iter).
__global__ __launch_bounds__(512, 4) void k_probe(const int* __restrict__ v_int,
                                                  const int* __restrict__ Np,
                                                  float* __restrict__ out) {
    __shared__ float partial[8];

    const int tid = threadIdx.x;
    const int lane = tid & 63;
    const int w = tid >> 6;
    const int m = lane & 15;
    const int q = lane >> 4;

    const int bid = blockIdx.x;
    const int probe = bid >> 5;          // 0..15
    const int btile = bid & 31;          // 0..31 (128 rows each)
    const int r0 = btile * 128 + w * 16; // wave's 16-row b-tile

    const float Nf = (float)(*Np);
    const float temper = Nf / (Nf + 1.0f);

    const size_t PB = (size_t)Bsz * Dn;
    // lane (m,q): v row r0+m, d-offset q*8 within each 32-d chunk
    const char* vg = (const char*)(v_int + (size_t)probe * PB + (size_t)(r0 + m) * Dn) + q * 32;
    // mu B-frag base for lane: row kt*16+m, d-offset dc*32 + q*8
    const unsigned short* mub = g_mu_bf + (size_t)m * Dn + q * 8;

    // 4-deep rolling v window (statically indexed under full unroll)
    int4 vb[4][2];
#pragma unroll
    for (int c = 0; c < 4; ++c) {
        vb[c][0] = *(const int4*)(vg + c * 128);
        vb[c][1] = *(const int4*)(vg + c * 128 + 16);
    }

    floatx4 acc[8];
#pragma unroll
    for (int kt = 0; kt < 8; ++kt) acc[kt] = (floatx4){0.f, 0.f, 0.f, 0.f};

#pragma unroll
    for (int dc = 0; dc < 16; ++dc) {
        int4 w0 = vb[dc & 3][0], w1 = vb[dc & 3][1];
        if (dc < 12) {  // refill slot with chunk dc+4 (4 chunks of slack)
            vb[dc & 3][0] = *(const int4*)(vg + (dc + 4) * 128);
            vb[dc & 3][1] = *(const int4*)(vg + (dc + 4) * 128 + 16);
        }
        // bf16(2v-1): v=1 -> 0x3F80, v=0 -> 0xBF80 == 0xBF80 ^ (v<<15)
        union { uint32_t u[4]; shortx8 s; } af;
        af.u[0] = 0xBF80BF80u ^ ((uint32_t)w0.x << 15) ^ ((uint32_t)w0.y << 31);
        af.u[1] = 0xBF80BF80u ^ ((uint32_t)w0.z << 15) ^ ((uint32_t)w0.w << 31);
        af.u[2] = 0xBF80BF80u ^ ((uint32_t)w1.x << 15) ^ ((uint32_t)w1.y << 31);
        af.u[3] = 0xBF80BF80u ^ ((uint32_t)w1.z << 15) ^ ((uint32_t)w1.w << 31);
#pragma unroll
        for (int kt = 0; kt < 8; ++kt) {
            shortx8 bf = *(const shortx8*)(mub + (size_t)kt * 16 * Dn + dc * 32);
            acc[kt] = __builtin_amdgcn_mfma_f32_16x16x32_bf16(af.s, bf, acc[kt], 0, 0, 0);
        }
    }

    // ---- epilogue: s1 = sum_k w*T^2, s2 = sum_k w*T per b-row ----
    float contrib = 0.f;
#pragma unroll
    for (int i = 0; i < 4; ++i) {
        const float* wrow = g_w + (size_t)(r0 + q * 4 + i) * Kn + m;
        float s1 = 0.f, s2 = 0.f;
#pragma unroll
        for (int kt = 0; kt < 8; ++kt) {
            float T = acc[kt][i];
            float ww = wrow[kt * 16];
            s1 = fmaf(ww * T, T, s1);
            s2 = fmaf(ww, T, s2);
        }
        s1 = rowsum16(s1);
        s2 = rowsum16(s2);
        contrib += s1 - s2 * s2;
    }
    if (m != 0) contrib = 0.f;           // rowsum16 replicated across m-lanes
    contrib += __shfl_xor(contrib, 16);
    contrib += __shfl_xor(contrib, 32);
    if (lane == 0) partial[w] = contrib;
    __syncthreads();
    if (tid == 0) {
        float t = 0.f;
#pragma unroll
        for (int i = 0; i < 8; ++i) t += partial[i];
        atomicAdd(out, t * temper * (1.0f / (float)Pn) * (1.0f / (float)Bsz));
    }
}

extern "C" void kernel_launch(void* const* d_in, const int* in_sizes, int n_in,
                              void* d_out, int out_size, void* d_ws, size_t ws_size,
                              hipStream_t stream) {
    const float* thetas = (const float*)d_in[0];
    const float* alpha  = (const float*)d_in[1];
    const float* W      = (const float*)d_in[2];
    const int*   v_int  = (const int*)d_in[3];
    const int*   Np     = (const int*)d_in[4];
    (void)d_ws; (void)ws_size;

    float* out = (float*)d_out;
    k_mu   <<<dim3(Kn),  dim3(256), 0, stream>>>(alpha, W, out);
    k_w    <<<dim3(256), dim3(512), 0, stream>>>(thetas, Np, out);
    k_probe<<<dim3(512), dim3(512), 0, stream>>>(v_int, Np, out);
}

// Round 7
// 223.205 us; speedup vs baseline: 1.1687x; 1.1430x over previous
//
#include <hip/hip_runtime.h>
#include <hip/hip_bf16.h>
#include <stdint.h>

#define Bsz 4096
#define Dn  512
#define Kn  128
#define Pn  16
#define An  32
#define TB  16

typedef __attribute__((ext_vector_type(4))) float  floatx4;
typedef __attribute__((ext_vector_type(8))) short  shortx8;

// Module-scope scratch (d_ws unused — harness poison fills are unconditional).
__device__ unsigned short g_mu_bf[Kn * Dn];
__device__ unsigned short g_mu_t[Dn * Kn];
__device__ float          g_munorm[Kn];
__device__ float          g_w[Bsz * Kn];       // softmax weights, f32 (2 MB, L2/L3)

__device__ __forceinline__ unsigned short f2bf(float x) {
    union { float f; uint32_t u; } v; v.f = x;
    uint32_t u = v.u;
    uint32_t r = (u + 0x7FFFu + ((u >> 16) & 1u)) >> 16;
    return (unsigned short)r;
}

// Sum over the 16 lanes of a DPP row (m = lane&15), pure VALU.
__device__ __forceinline__ float rowsum16(float x) {
    x += __int_as_float(__builtin_amdgcn_update_dpp(0, __float_as_int(x), 0xB1, 0xF, 0xF, false));
    x += __int_as_float(__builtin_amdgcn_update_dpp(0, __float_as_int(x), 0x4E, 0xF, 0xF, false));
    x += __int_as_float(__builtin_amdgcn_update_dpp(0, __float_as_int(x), 0x124, 0xF, 0xF, false));
    x += __int_as_float(__builtin_amdgcn_update_dpp(0, __float_as_int(x), 0x128, 0xF, 0xF, false));
    return x;
}

// ---------------- K1: mu = alpha @ W (bf16 + transposed) + ||mu_k||^2 ----------------
__global__ __launch_bounds__(256) void k_mu(const float* __restrict__ alpha,
                                            const float* __restrict__ W,
                                            float* __restrict__ out) {
    __shared__ float al[An];
    __shared__ float red[4];
    int k = blockIdx.x, t = threadIdx.x;
    if (k == 0 && t == 0) *out = 0.f;
    if (t < An) al[t] = alpha[k * An + t];
    __syncthreads();
    int d0 = t, d1 = t + 256;
    float a0 = 0.f, a1 = 0.f;
#pragma unroll
    for (int a = 0; a < An; ++a) {
        float av = al[a];
        a0 = fmaf(av, W[a * Dn + d0], a0);
        a1 = fmaf(av, W[a * Dn + d1], a1);
    }
    unsigned short h0 = f2bf(a0), h1 = f2bf(a1);
    g_mu_bf[k * Dn + d0] = h0;  g_mu_bf[k * Dn + d1] = h1;
    g_mu_t[d0 * Kn + k] = h0;   g_mu_t[d1 * Kn + k] = h1;
    float nrm = a0 * a0 + a1 * a1;
#pragma unroll
    for (int msk = 1; msk < 64; msk <<= 1) nrm += __shfl_xor(nrm, msk);
    if ((t & 63) == 0) red[t >> 6] = nrm;
    __syncthreads();
    if (t == 0) g_munorm[k] = red[0] + red[1] + red[2] + red[3];
}

// ---------------- K2: S = theta@mu^T, softmax -> g_w, wGw + lossA ----------------
__global__ __launch_bounds__(512) void k_w(const float* __restrict__ thetas,
                                           const int* __restrict__ Np,
                                           float* __restrict__ out) {
    __shared__ short vt[TB][520];
    __shared__ float S_l[TB][132];
    __shared__ float w_l[TB][132];
    __shared__ short wbf[TB][136];
    __shared__ float part8[8][TB];
    __shared__ float thn[TB];
    __shared__ float SwS[TB];

    const int tid = threadIdx.x;
    const int lane = tid & 63;
    const int wv = tid >> 6;
    const int m = lane & 15;
    const int q = lane >> 4;
    const int b0 = blockIdx.x * TB;

    const float Nf = (float)(*Np);
    const float temper = Nf / (Nf + 1.0f);

    const int kcol = wv * 16 + m;
    shortx8 mufrag[16];
    {
        const unsigned short* mb = g_mu_bf + (size_t)kcol * Dn + q * 8;
#pragma unroll
        for (int dc = 0; dc < 16; ++dc)
            mufrag[dc] = *(const shortx8*)(mb + dc * 32);
    }

    const int r = tid >> 5;
    const int c0 = (tid & 31) * 16;
    {   // stage theta -> vt (bf16), ||theta||^2 fp32
        const float4* tg = (const float4*)(thetas + (size_t)(b0 + r) * Dn + c0);
        float tn = 0.f;
#pragma unroll
        for (int j = 0; j < 4; ++j) {
            float4 f = tg[j];
            tn += f.x * f.x + f.y * f.y + f.z * f.z + f.w * f.w;
            short4 h;
            h.x = (short)f2bf(f.x); h.y = (short)f2bf(f.y);
            h.z = (short)f2bf(f.z); h.w = (short)f2bf(f.w);
            *(short4*)&vt[r][c0 + j * 4] = h;
        }
#pragma unroll
        for (int msk = 1; msk < 32; msk <<= 1) tn += __shfl_xor(tn, msk);
        if ((tid & 31) == 0) thn[r] = tn;
    }
    __syncthreads();

    // ---- S = theta @ mu^T ----
    {
        floatx4 acc = {0.f, 0.f, 0.f, 0.f};
#pragma unroll
        for (int dc = 0; dc < 16; ++dc) {
            shortx8 a = *(const shortx8*)&vt[m][dc * 32 + q * 8];
            acc = __builtin_amdgcn_mfma_f32_16x16x32_bf16(a, mufrag[dc], acc, 0, 0, 0);
        }
#pragma unroll
        for (int i = 0; i < 4; ++i) S_l[q * 4 + i][kcol] = acc[i];
    }
    __syncthreads();

    // ---- softmax over k (32 threads per b-row); also writes g_w ----
    {
        const int b = tid >> 5, s = tid & 31;
        float l[4];
        float mx = -3.4e38f;
        float tnb = thn[b];
#pragma unroll
        for (int j = 0; j < 4; ++j) {
            int k = s + 32 * j;
            l[j] = -0.5f * (tnb - 2.f * S_l[b][k] + g_munorm[k]);
            mx = fmaxf(mx, l[j]);
        }
#pragma unroll
        for (int msk = 1; msk < 32; msk <<= 1) mx = fmaxf(mx, __shfl_xor(mx, msk));
        float se = 0.f, ses = 0.f;
        float e[4];
#pragma unroll
        for (int j = 0; j < 4; ++j) {
            int k = s + 32 * j;
            e[j] = __expf(l[j] - mx);
            se += e[j];
            ses += e[j] * S_l[b][k];
        }
#pragma unroll
        for (int msk = 1; msk < 32; msk <<= 1) { se += __shfl_xor(se, msk); ses += __shfl_xor(ses, msk); }
        float inv = 1.f / se;
#pragma unroll
        for (int j = 0; j < 4; ++j) {
            int k = s + 32 * j;
            float wvv = e[j] * inv;
            w_l[b][k] = wvv;
            wbf[b][k] = (short)f2bf(wvv);
            g_w[(size_t)(b0 + b) * Kn + k] = wvv;   // coalesced global write
        }
        if (s == 0) SwS[b] = ses * inv;
    }
    __syncthreads();

    // ---- wGw = ||w @ mu||^2 (from g_mu_t, L2-resident) ----
    {
        float sg[4] = {0.f, 0.f, 0.f, 0.f};
#pragma unroll
        for (int ct = 0; ct < 4; ++ct) {
            const unsigned short* mt = g_mu_t + (size_t)(wv * 64 + ct * 16 + m) * Kn + q * 8;
            floatx4 acc = {0.f, 0.f, 0.f, 0.f};
#pragma unroll
            for (int kc = 0; kc < 4; ++kc) {
                shortx8 a = *(const shortx8*)&wbf[m][kc * 32 + q * 8];
                shortx8 bfr = *(const shortx8*)(mt + kc * 32);
                acc = __builtin_amdgcn_mfma_f32_16x16x32_bf16(a, bfr, acc, 0, 0, 0);
            }
#pragma unroll
            for (int i = 0; i < 4; ++i) sg[i] += acc[i] * acc[i];
        }
#pragma unroll
        for (int i = 0; i < 4; ++i) sg[i] = rowsum16(sg[i]);
        if (m == 0) {
#pragma unroll
            for (int i = 0; i < 4; ++i) part8[wv][q * 4 + i] = sg[i];
        }
    }
    __syncthreads();

    if (tid < TB) {
        float wGw = 0.f;
#pragma unroll
        for (int w8 = 0; w8 < 8; ++w8) wGw += part8[w8][tid];
        float res = 0.5f * temper * temper * (wGw - 2.f * SwS[tid] + thn[tid])
                    - temper * (float)Dn;
#pragma unroll
        for (int msk = 1; msk < 16; msk <<= 1) res += __shfl_xor(res, msk);
        if (tid == 0) atomicAdd(out, res * (1.0f / (float)Bsz));
    }
}

// ---------------- K3: probe trace, mu resident in LDS per CU ----------------
// 256 blocks x 1024 thr (16 waves), 1 block/CU (mu 128 KB LDS + w 8.4 KB).
// Block bt owns b-rows [bt*16, bt*16+16); wave wv = probe. mu staged ONCE
// (XOR-swizzled, T2 pattern: lanes read 16 different rows at same col-range),
// then each wave: 32 coalesced v loads -> A-frags, 128 conflict-free
// ds_read_b128 B-frags, 128 MFMA. Fixes r6's limiter: 172k VMEM
// gather-instructions/CU (mu re-gathered from L2 per wave, 512 MB flow)
// -> ~1.5k VMEM instr/CU; LDS mu flow 2 MB/CU = 16k cyc < 48k cyc HBM floor.
__global__ __launch_bounds__(1024, 4) void k_probe(const int* __restrict__ v_int,
                                                   const int* __restrict__ Np,
                                                   float* __restrict__ out) {
    __shared__ __align__(16) unsigned short mu_l[Kn * Dn];  // 128 KB, swizzled
    __shared__ float w_l[TB][132];                           // 8.4 KB
    __shared__ float partial[16];

    const int tid = threadIdx.x;
    const int lane = tid & 63;
    const int wv = tid >> 6;          // 0..15 = probe
    const int m = lane & 15;
    const int q = lane >> 4;
    const int bt = blockIdx.x;        // 0..255
    const int r0 = bt * TB;

    const float Nf = (float)(*Np);
    const float temper = Nf / (Nf + 1.0f);

    // ---- stage mu into LDS, XOR-swizzled: byte = row*1024 + (off ^ ((row&7)<<4)) ----
    {
        const int4* src = (const int4*)g_mu_bf;
#pragma unroll
        for (int i = 0; i < 8; ++i) {
            int c = i * 1024 + tid;                 // 16B chunk id, 8192 total
            int row = c >> 6;                        // 64 chunks per 1 KB row
            int off = (c & 63) * 16;
            int4 val = src[c];
            *(int4*)((char*)mu_l + row * 1024 + (off ^ ((row & 7) << 4))) = val;
        }
    }
    // ---- stage w for the block's 16 rows ----
    if (tid < 512) {
        int row = tid >> 5, c = (tid & 31) * 4;
        float4 w4 = *(const float4*)(g_w + (size_t)(r0 + row) * Kn + c);
        *(float4*)&w_l[row][c] = w4;
    }
    __syncthreads();   // only block-wide barrier before the epilogue

    const size_t PB = (size_t)Bsz * Dn;
    // lane (m,q): v row r0+m of probe wv, 32 B at q*32 within each 128 B chunk
    const char* vg = (const char*)(v_int + (size_t)wv * PB + (size_t)(r0 + m) * Dn) + q * 32;

    // 4-deep rolling v window (statically indexed under full unroll)
    int4 vb[4][2];
#pragma unroll
    for (int c = 0; c < 4; ++c) {
        vb[c][0] = *(const int4*)(vg + c * 128);
        vb[c][1] = *(const int4*)(vg + c * 128 + 16);
    }

    floatx4 acc[8];
#pragma unroll
    for (int kt = 0; kt < 8; ++kt) acc[kt] = (floatx4){0.f, 0.f, 0.f, 0.f};

    const int swz = (m & 7) << 4;     // row&7 == m&7 (kt*16 ≡ 0 mod 8)
#pragma unroll
    for (int dc = 0; dc < 16; ++dc) {
        int4 w0 = vb[dc & 3][0], w1 = vb[dc & 3][1];
        if (dc < 12) {
            vb[dc & 3][0] = *(const int4*)(vg + (dc + 4) * 128);
            vb[dc & 3][1] = *(const int4*)(vg + (dc + 4) * 128 + 16);
        }
        // bf16(2v-1): v=1 -> 0x3F80, v=0 -> 0xBF80 == 0xBF80 ^ (v<<15)
        union { uint32_t u[4]; shortx8 s; } af;
        af.u[0] = 0xBF80BF80u ^ ((uint32_t)w0.x << 15) ^ ((uint32_t)w0.y << 31);
        af.u[1] = 0xBF80BF80u ^ ((uint32_t)w0.z << 15) ^ ((uint32_t)w0.w << 31);
        af.u[2] = 0xBF80BF80u ^ ((uint32_t)w1.x << 15) ^ ((uint32_t)w1.y << 31);
        af.u[3] = 0xBF80BF80u ^ ((uint32_t)w1.z << 15) ^ ((uint32_t)w1.w << 31);
        const int boff = dc * 64 + q * 16;
#pragma unroll
        for (int kt = 0; kt < 8; ++kt) {
            shortx8 bf = *(const shortx8*)((const char*)mu_l
                              + (kt * 16 + m) * 1024 + (boff ^ swz));
            acc[kt] = __builtin_amdgcn_mfma_f32_16x16x32_bf16(af.s, bf, acc[kt], 0, 0, 0);
        }
    }

    // ---- epilogue: s1 = sum_k w*T^2, s2 = sum_k w*T per b-row ----
    float contrib = 0.f;
#pragma unroll
    for (int i = 0; i < 4; ++i) {
        float s1 = 0.f, s2 = 0.f;
#pragma unroll
        for (int kt = 0; kt < 8; ++kt) {
            float T = acc[kt][i];
            float ww = w_l[q * 4 + i][kt * 16 + m];
            s1 = fmaf(ww * T, T, s1);
            s2 = fmaf(ww, T, s2);
        }
        s1 = rowsum16(s1);
        s2 = rowsum16(s2);
        contrib += s1 - s2 * s2;
    }
    if (m != 0) contrib = 0.f;        // rowsum16 replicated across m-lanes
    contrib += __shfl_xor(contrib, 16);
    contrib += __shfl_xor(contrib, 32);
    if (lane == 0) partial[wv] = contrib;
    __syncthreads();
    if (tid == 0) {
        float t = 0.f;
#pragma unroll
        for (int i = 0; i < 16; ++i) t += partial[i];
        atomicAdd(out, t * temper * (1.0f / (float)Pn) * (1.0f / (float)Bsz));
    }
}

extern "C" void kernel_launch(void* const* d_in, const int* in_sizes, int n_in,
                              void* d_out, int out_size, void* d_ws, size_t ws_size,
                              hipStream_t stream) {
    const float* thetas = (const float*)d_in[0];
    const float* alpha  = (const float*)d_in[1];
    const float* W      = (const float*)d_in[2];
    const int*   v_int  = (const int*)d_in[3];
    const int*   Np     = (const int*)d_in[4];
    (void)d_ws; (void)ws_size;

    float* out = (float*)d_out;
    k_mu   <<<dim3(Kn),  dim3(256),  0, stream>>>(alpha, W, out);
    k_w    <<<dim3(256), dim3(512),  0, stream>>>(thetas, Np, out);
    k_probe<<<dim3(256), dim3(1024), 0, stream>>>(v_int, Np, out);
}